// Round 5
// baseline (221.558 us; speedup 1.0000x reference)
//
#include <hip/hip_runtime.h>

#define D 128
#define GEMM_BLOCKS 512
#define NXCD 8

typedef unsigned short ushort_t;
typedef short short8 __attribute__((ext_vector_type(8)));
typedef ushort_t ushort8v __attribute__((ext_vector_type(8)));
typedef float f32x4 __attribute__((ext_vector_type(4)));

static __device__ __forceinline__ unsigned short f2bf(float f){
  unsigned int b = __float_as_uint(f);
  unsigned int r = (b + 0x7FFFu + ((b >> 16) & 1u)) >> 16;
  return (unsigned short)r;
}
static __device__ __forceinline__ float bf2f(unsigned short u){
  return __uint_as_float(((unsigned int)u) << 16);
}

// Physical XCD id (HW_REG_XCC_ID = hwreg 20; returns 0..7 on MI355X).
static __device__ __forceinline__ int xcc_id(){
  unsigned x;
  asm volatile("s_getreg_b32 %0, hwreg(20, 0, 8)" : "=s"(x));
  return (int)(x & (NXCD - 1));
}

// ---------------- U1: count (XCD-local atomic ranks) UNION wmerge ----------------
// blocks [0,128): wmerge row r = blockIdx; blocks [128, ...): count chunk.
// Each XCD increments its own replica cnt8[x][key] with a WORKGROUP-scope
// (L2-local) atomic; rank packs (xcd<<24)|local_rank.

__global__ void k_u1(const int* __restrict__ node_idx, const int* __restrict__ hedge_idx,
                     int ni, int* __restrict__ cnt8_v, int* __restrict__ cnt8_e,
                     int nv, int ne,
                     int* __restrict__ rank_v, int* __restrict__ rank_e,
                     const float* __restrict__ W1, const float* __restrict__ Wve,
                     const float* __restrict__ b1, const float* __restrict__ bve,
                     ushort_t* __restrict__ Wc, float* __restrict__ bc){
  int t = threadIdx.x;
  if (blockIdx.x < 128){
    int r = blockIdx.x;
    if (t < D){
      float acc = 0.f;
      for (int k = 0; k < D; ++k)
        acc += Wve[r * D + k] * W1[k * D + t];
      Wc[r * D + t] = f2bf(acc);
      if (t == 0){
        float s = 0.f;
        for (int k = 0; k < D; ++k) s += Wve[r * D + k] * b1[k];
        bc[r] = s + bve[r];
      }
    }
  } else {
    int i = (blockIdx.x - 128) * 256 + t;
    if (i < ni){
      int x = xcc_id();
      int v = node_idx[i];
      int e = hedge_idx[i];
      int rv = __hip_atomic_fetch_add(&cnt8_v[x * nv + v], 1,
                                      __ATOMIC_RELAXED, __HIP_MEMORY_SCOPE_WORKGROUP);
      int re = __hip_atomic_fetch_add(&cnt8_e[x * ne + e], 1,
                                      __ATOMIC_RELAXED, __HIP_MEMORY_SCOPE_WORKGROUP);
      rank_v[i] = (x << 24) | rv;
      rank_e[i] = (x << 24) | re;
    }
  }
}

// ---------------- replica reduce: totals + in-place per-XCD exclusive bases ----

__global__ void k_reduce8(int* __restrict__ cnt8_v, int nv, int* __restrict__ cnt_v,
                          int* __restrict__ cnt8_e, int ne, int* __restrict__ cnt_e){
  int i = blockIdx.x * 256 + threadIdx.x;
  if (i < nv){
    int c[NXCD];
#pragma unroll
    for (int x = 0; x < NXCD; ++x) c[x] = cnt8_v[x * nv + i];
    int tot = 0;
#pragma unroll
    for (int x = 0; x < NXCD; ++x){ int cc = c[x]; cnt8_v[x * nv + i] = tot; tot += cc; }
    cnt_v[i] = tot;
  } else if (i < nv + ne){
    int k = i - nv;
    int c[NXCD];
#pragma unroll
    for (int x = 0; x < NXCD; ++x) c[x] = cnt8_e[x * ne + k];
    int tot = 0;
#pragma unroll
    for (int x = 0; x < NXCD; ++x){ int cc = c[x]; cnt8_e[x * ne + k] = tot; tot += cc; }
    cnt_e[k] = tot;
  }
}

// ---------------- fused scans (e then v) ----------------

__device__ __forceinline__ void scan_partial_body(const int* cnt, int n, int* bsum, int b){
  __shared__ int s[256];
  int t = threadIdx.x;
  int base = b * 1024;
  int acc = 0;
  for (int j = t; j < 1024; j += 256){
    int idx = base + j;
    if (idx < n) acc += cnt[idx];
  }
  s[t] = acc; __syncthreads();
  for (int o = 128; o > 0; o >>= 1){
    if (t < o) s[t] += s[t + o];
    __syncthreads();
  }
  if (t == 0) bsum[b] = s[0];
}

__global__ void k_scan_partial2(const int* __restrict__ cnt_e, int ne, int* __restrict__ bsum_e,
                                const int* __restrict__ cnt_v, int nv, int* __restrict__ bsum_v,
                                int nbe){
  if ((int)blockIdx.x < nbe) scan_partial_body(cnt_e, ne, bsum_e, blockIdx.x);
  else                       scan_partial_body(cnt_v, nv, bsum_v, blockIdx.x - nbe);
}

__device__ __forceinline__ void scan_bsums_body(int* bsum, int nb){
  __shared__ int s[256];
  int t = threadIdx.x;
  int runbase = 0;
  for (int base = 0; base < nb; base += 256){
    int v = (base + t < nb) ? bsum[base + t] : 0;
    s[t] = v;
    __syncthreads();
    for (int o = 1; o < 256; o <<= 1){
      int x = (t >= o) ? s[t - o] : 0;
      __syncthreads();
      s[t] += x;
      __syncthreads();
    }
    int total = s[255];
    if (base + t < nb) bsum[base + t] = runbase + (s[t] - v);  // exclusive
    __syncthreads();
    runbase += total;
  }
}

__global__ void k_scan_bsums2(int* __restrict__ bsum_e, int nbe,
                              int* __restrict__ bsum_v, int nbv){
  if (blockIdx.x == 0) scan_bsums_body(bsum_e, nbe);
  else                 scan_bsums_body(bsum_v, nbv);
}

// final scan also emits per-key fused slot table: tab[key*8+x] = off[key] + xb[x][key]
__device__ __forceinline__ void scan_final_body(const int* cnt, int n, const int* bsum,
                                                int* off, const int* xb, int* tab, int b){
  __shared__ int s[256];
  int t = threadIdx.x;
  int base = b * 1024 + t * 4;
  int v0 = (base + 0 < n) ? cnt[base + 0] : 0;
  int v1 = (base + 1 < n) ? cnt[base + 1] : 0;
  int v2 = (base + 2 < n) ? cnt[base + 2] : 0;
  int v3 = (base + 3 < n) ? cnt[base + 3] : 0;
  int lsum = v0 + v1 + v2 + v3;
  s[t] = lsum; __syncthreads();
  for (int o = 1; o < 256; o <<= 1){
    int x = (t >= o) ? s[t - o] : 0;
    __syncthreads();
    s[t] += x;
    __syncthreads();
  }
  int excl = s[t] - lsum + bsum[b];
  int offs[4];
  offs[0] = excl;
  offs[1] = excl + v0;
  offs[2] = excl + v0 + v1;
  offs[3] = excl + v0 + v1 + v2;
#pragma unroll
  for (int q = 0; q < 4; ++q){
    int key = base + q;
    if (key < n){
      off[key] = offs[q];
#pragma unroll
      for (int x = 0; x < NXCD; ++x)
        tab[key * NXCD + x] = offs[q] + xb[x * n + key];
    }
  }
}

__global__ void k_scan_final2(const int* __restrict__ cnt_e, int ne, const int* __restrict__ bsum_e,
                              int* __restrict__ off_e, const int* __restrict__ xb_e, int* __restrict__ tab_e,
                              const int* __restrict__ cnt_v, int nv, const int* __restrict__ bsum_v,
                              int* __restrict__ off_v, const int* __restrict__ xb_v, int* __restrict__ tab_v,
                              int nbe){
  if ((int)blockIdx.x < nbe) scan_final_body(cnt_e, ne, bsum_e, off_e, xb_e, tab_e, blockIdx.x);
  else                       scan_final_body(cnt_v, nv, bsum_v, off_v, xb_v, tab_v, blockIdx.x - nbe);
}

// ---------------- MFMA GEMM body ----------------
// out(bf16)[M x 128] = A[M x 128] @ Wb(bf16).T + bias. A is f32 or bf16.
// Tile: 64 rows x 128 cols, 4 waves; B fragments in registers; A-tile in LDS,
// XOR-swizzled (ushort col8 ^ ((row&7)<<3)).

template<bool BF16IN>
__device__ __forceinline__ void gemm_body(const void* __restrict__ A_,
                                          const ushort_t* __restrict__ Wb,
                                          const float* __restrict__ bias,
                                          ushort_t* __restrict__ out, int M,
                                          int bid, int nblocks, ushort_t* Al){
  const int t = threadIdx.x;
  const int w = t >> 6;
  const int l = t & 63;
  const int l15 = l & 15;
  const int lh = l >> 4;            // 0..3

  short8 breg[4][8];
#pragma unroll
  for (int kc = 0; kc < 4; ++kc)
#pragma unroll
    for (int n0 = 0; n0 < 8; ++n0)
      breg[kc][n0] = *(const short8*)&Wb[(n0 * 16 + l15) * D + kc * 32 + lh * 8];

  float bias_r[8];
#pragma unroll
  for (int n0 = 0; n0 < 8; ++n0) bias_r[n0] = bias[n0 * 16 + l15];

  const int r_st = t >> 2;          // staging row 0..63
  const int q_st = t & 3;           // k-quarter (32 cols)
  const int ntile = (M + 63) >> 6;

  for (int tile = bid; tile < ntile; tile += nblocks){
    const int row0 = tile << 6;
    __syncthreads();
    {
      int r = row0 + r_st;
      ushort8v h[4];
      if (r < M){
        if (BF16IN){
          const ushort8v* src = (const ushort8v*)((const ushort_t*)A_ + (size_t)r * D + q_st * 32);
#pragma unroll
          for (int c = 0; c < 4; ++c) h[c] = src[c];
        } else {
          const float4* src = (const float4*)((const float*)A_ + (size_t)r * D + q_st * 32);
          float4 v[8];
#pragma unroll
          for (int i = 0; i < 8; ++i) v[i] = src[i];
#pragma unroll
          for (int c = 0; c < 4; ++c){
            h[c][0] = f2bf(v[2*c].x);   h[c][1] = f2bf(v[2*c].y);
            h[c][2] = f2bf(v[2*c].z);   h[c][3] = f2bf(v[2*c].w);
            h[c][4] = f2bf(v[2*c+1].x); h[c][5] = f2bf(v[2*c+1].y);
            h[c][6] = f2bf(v[2*c+1].z); h[c][7] = f2bf(v[2*c+1].w);
          }
        }
      } else {
#pragma unroll
        for (int c = 0; c < 4; ++c) h[c] = (ushort8v){0,0,0,0,0,0,0,0};
      }
#pragma unroll
      for (int c = 0; c < 4; ++c){
        int col = q_st * 32 + c * 8;
        int swz = col ^ ((r_st & 7) << 3);
        *(ushort8v*)&Al[r_st * D + swz] = h[c];
      }
    }
    __syncthreads();

    f32x4 acc[8];
#pragma unroll
    for (int n0 = 0; n0 < 8; ++n0) acc[n0] = (f32x4){0.f, 0.f, 0.f, 0.f};

#pragma unroll
    for (int kc = 0; kc < 4; ++kc){
      const int arow = w * 16 + l15;
      const int acol = (kc * 32 + lh * 8) ^ ((l15 & 7) << 3);
      short8 a = *(const short8*)&Al[arow * D + acol];
#pragma unroll
      for (int n0 = 0; n0 < 8; ++n0)
        acc[n0] = __builtin_amdgcn_mfma_f32_16x16x32_bf16(a, breg[kc][n0], acc[n0], 0, 0, 0);
    }

    // C/D layout: col = lane&15, row = (lane>>4)*4 + reg
    const int rbase = row0 + w * 16 + lh * 4;
#pragma unroll
    for (int n0 = 0; n0 < 8; ++n0){
      const int colo = n0 * 16 + l15;
#pragma unroll
      for (int rg = 0; rg < 4; ++rg){
        int row = rbase + rg;
        if (row < M) out[(size_t)row * D + colo] = f2bf(acc[n0][rg] + bias_r[n0]);
      }
    }
  }
}

template<bool BF16IN>
__global__ __launch_bounds__(256, 2)
void k_gemm(const void* __restrict__ A_, const ushort_t* __restrict__ Wb,
            const float* __restrict__ bias, ushort_t* __restrict__ out, int M){
  __shared__ ushort_t Al[64 * D];
  gemm_body<BF16IN>(A_, Wb, bias, out, M, blockIdx.x, gridDim.x, Al);
}

// ---------------- U2: gemm1 (f32 in) UNION CSR fill (table-based) ----------------

__global__ __launch_bounds__(256, 2)
void k_u2(const float* __restrict__ A, const ushort_t* __restrict__ Wb,
          const float* __restrict__ bias, ushort_t* __restrict__ out, int M,
          const int* __restrict__ node_idx, const int* __restrict__ hedge_idx,
          const int* __restrict__ rank_v, const int* __restrict__ rank_e, int ni,
          const int* __restrict__ tab_v, const int* __restrict__ tab_e,
          int* __restrict__ vlist_e, int* __restrict__ elist_v){
  __shared__ ushort_t Al[64 * D];
  if (blockIdx.x < GEMM_BLOCKS){
    gemm_body<false>(A, Wb, bias, out, M, blockIdx.x, GEMM_BLOCKS, Al);
  } else {
    int i = (blockIdx.x - GEMM_BLOCKS) * 256 + threadIdx.x;
    if (i < ni){
      int v = node_idx[i];
      int e = hedge_idx[i];
      int re = rank_e[i];
      int rv = rank_v[i];
      int pe = tab_e[e * NXCD + (re >> 24)] + (re & 0xFFFFFF);
      __builtin_nontemporal_store(v, &elist_v[pe]);
      int pv = tab_v[v * NXCD + (rv >> 24)] + (rv & 0xFFFFFF);
      __builtin_nontemporal_store(e, &vlist_e[pv]);
    }
  }
}

// ---------------- weighted segment gather-sum, 4 items/iter ----------------

template<bool BF16OUT>
__global__ void k_scatter4(const ushort_t* __restrict__ src,
                           const int* __restrict__ off, const int* __restrict__ cnt,
                           const int* __restrict__ list,
                           const float* __restrict__ wnum, const float* __restrict__ dsum,
                           void* __restrict__ dst_, int nseg){
  int gw = (blockIdx.x * 256 + threadIdx.x) >> 6;
  if (gw >= nseg) return;
  int lane = threadIdx.x & 63;
  int l15 = lane & 15;
  int g = lane >> 4;
  int s = __builtin_amdgcn_readfirstlane(off[gw]);
  int n = __builtin_amdgcn_readfirstlane(cnt[gw]);
  float inv = 1.0f / dsum[gw];

  float acc[8];
#pragma unroll
  for (int c = 0; c < 8; ++c) acc[c] = 0.f;

  for (int j = 0; j < n; j += 4){
    int jj = j + g;
    bool ok = jj < n;
    int r = list[s + (ok ? jj : 0)];
    float wt = ok ? wnum[r] * inv : 0.f;
    ushort8v x = *(const ushort8v*)&src[(size_t)r * D + l15 * 8];
#pragma unroll
    for (int c = 0; c < 8; ++c) acc[c] += wt * bf2f(x[c]);
  }

#pragma unroll
  for (int c = 0; c < 8; ++c){
    acc[c] += __shfl_xor(acc[c], 16);
    acc[c] += __shfl_xor(acc[c], 32);
  }

  if (g == 0){
    if (BF16OUT){
      ushort8v h;
#pragma unroll
      for (int c = 0; c < 8; ++c) h[c] = f2bf(acc[c]);
      *(ushort8v*)((ushort_t*)dst_ + (size_t)gw * D + l15 * 8) = h;
    } else {
      float* dp = (float*)dst_ + (size_t)gw * D + l15 * 8;
      float4 o0, o1;
      o0.x = acc[0]; o0.y = acc[1]; o0.z = acc[2]; o0.w = acc[3];
      o1.x = acc[4]; o1.y = acc[5]; o1.z = acc[6]; o1.w = acc[7];
      *(float4*)dp = o0;
      *(float4*)(dp + 4) = o1;
    }
  }
}

// ---------------- weight convert ----------------

__global__ void k_wconv(const float* __restrict__ W, ushort_t* __restrict__ Wb){
  int i = blockIdx.x * 256 + threadIdx.x;
  if (i < D * D) Wb[i] = f2bf(W[i]);
}

// ---------------- host ----------------

static inline int cdiv(int a, int b){ return (a + b - 1) / b; }

extern "C" void kernel_launch(void* const* d_in, const int* in_sizes, int n_in,
                              void* d_out, int out_size, void* d_ws, size_t ws_size,
                              hipStream_t stream){
  const float* vfeat        = (const float*)d_in[0];
  const float* v_reg_weight = (const float*)d_in[2];
  const float* v_reg_sum    = (const float*)d_in[3];
  const float* e_reg_weight = (const float*)d_in[4];
  const float* e_reg_sum    = (const float*)d_in[5];
  const int*   node_idx     = (const int*)d_in[6];
  const int*   hedge_idx    = (const int*)d_in[7];
  const float* W1  = (const float*)d_in[8];
  const float* b1  = (const float*)d_in[9];
  const float* Wve = (const float*)d_in[10];
  const float* bve = (const float*)d_in[11];
  const float* Wev = (const float*)d_in[12];
  const float* bev = (const float*)d_in[13];

  const int NV = in_sizes[2];
  const int NE = in_sizes[4];
  const int NI = in_sizes[6];

  char* p = (char*)d_ws;
  auto alloc = [&](size_t nbytes) -> void* {
    void* q = (void*)p;
    p += (nbytes + 255) & ~(size_t)255;
    return q;
  };

  char* zstart = p;
  int* cnt8_v = (int*)alloc((size_t)NXCD * NV * 4);  // replicas -> in-place excl bases
  int* cnt8_e = (int*)alloc((size_t)NXCD * NE * 4);
  size_t zbytes = (size_t)(p - zstart);

  int* cnt_v  = (int*)alloc((size_t)NV * 4);
  int* cnt_e  = (int*)alloc((size_t)NE * 4);
  int* off_v  = (int*)alloc((size_t)NV * 4);
  int* off_e  = (int*)alloc((size_t)NE * 4);
  int* tab_v  = (int*)alloc((size_t)NXCD * NV * 4);  // [key][x] fused slot bases
  int* tab_e  = (int*)alloc((size_t)NXCD * NE * 4);
  int* bsum_e = (int*)alloc(1024 * 4);
  int* bsum_v = (int*)alloc(1024 * 4);
  int* rank_v = (int*)alloc((size_t)NI * 4);
  int* rank_e = (int*)alloc((size_t)NI * 4);
  int* vlist_e = (int*)alloc((size_t)NI * 4);   // per vertex-slot: edge id
  int* elist_v = (int*)alloc((size_t)NI * 4);   // per edge-slot: vertex id
  ushort_t* Wc   = (ushort_t*)alloc((size_t)D * D * 2);
  ushort_t* Wevb = (ushort_t*)alloc((size_t)D * D * 2);
  float* bc      = (float*)alloc((size_t)D * 4);
  ushort_t* feat_e = (ushort_t*)alloc((size_t)NE * D * 2);
  ushort_t* Wh_e   = (ushort_t*)alloc((size_t)NE * D * 2);

  // Wh_n (bf16) lives in d_out's storage; fully overwritten by final scatter.
  ushort_t* Wh_n = (ushort_t*)d_out;

  hipMemsetAsync(zstart, 0, zbytes, stream);

  // U1: wmerge (blocks 0..127) + count-with-ranks via XCD-local atomics
  k_u1<<<128 + cdiv(NI, 256), 256, 0, stream>>>(node_idx, hedge_idx, NI,
                                                cnt8_v, cnt8_e, NV, NE,
                                                rank_v, rank_e,
                                                W1, Wve, b1, bve, Wc, bc);
  k_wconv<<<cdiv(D * D, 256), 256, 0, stream>>>(Wev, Wevb);

  // replica reduce: totals + in-place exclusive per-XCD bases
  k_reduce8<<<cdiv(NV + NE, 256), 256, 0, stream>>>(cnt8_v, NV, cnt_v, cnt8_e, NE, cnt_e);

  int nbe = cdiv(NE, 1024), nbv = cdiv(NV, 1024);
  k_scan_partial2<<<nbe + nbv, 256, 0, stream>>>(cnt_e, NE, bsum_e, cnt_v, NV, bsum_v, nbe);
  k_scan_bsums2<<<2, 256, 0, stream>>>(bsum_e, nbe, bsum_v, nbv);
  k_scan_final2<<<nbe + nbv, 256, 0, stream>>>(cnt_e, NE, bsum_e, off_e, cnt8_e, tab_e,
                                               cnt_v, NV, bsum_v, off_v, cnt8_v, tab_v, nbe);

  // U2: gemm1 (blocks 0..511, vfeat f32 -> Wh_n bf16) + CSR fill via tables
  k_u2<<<GEMM_BLOCKS + cdiv(NI, 256), 256, 0, stream>>>(vfeat, Wc, bc, Wh_n, NV,
                                                        node_idx, hedge_idx, rank_v, rank_e, NI,
                                                        tab_v, tab_e, vlist_e, elist_v);

  // node -> hyperedge: feat_e (bf16)
  k_scatter4<true><<<cdiv(NE * 64, 256), 256, 0, stream>>>(Wh_n, off_e, cnt_e, elist_v,
                                                           v_reg_weight, e_reg_sum,
                                                           feat_e, NE);

  // edge linear: Wh_e (bf16) = feat_e @ Wev.T + bev
  int g2 = cdiv(NE, 64); if (g2 > 512) g2 = 512;
  k_gemm<true><<<g2, 256, 0, stream>>>(feat_e, Wevb, bev, Wh_e, NE);

  // hyperedge -> node: d_out (f32)
  k_scatter4<false><<<cdiv(NV * 64, 256), 256, 0, stream>>>(Wh_e, off_v, cnt_v, vlist_e,
                                                            e_reg_weight, v_reg_sum,
                                                            d_out, NV);
}

// Round 6
// 218.926 us; speedup vs baseline: 1.0120x; 1.0120x over previous
//
#include <hip/hip_runtime.h>

#define D 128
#define GEMM_BLOCKS 512

typedef unsigned short ushort_t;
typedef short short8 __attribute__((ext_vector_type(8)));
typedef ushort_t ushort8v __attribute__((ext_vector_type(8)));
typedef float f32x4 __attribute__((ext_vector_type(4)));

static __device__ __forceinline__ unsigned short f2bf(float f){
  unsigned int b = __float_as_uint(f);
  unsigned int r = (b + 0x7FFFu + ((b >> 16) & 1u)) >> 16;
  return (unsigned short)r;
}
static __device__ __forceinline__ float bf2f(unsigned short u){
  return __uint_as_float(((unsigned int)u) << 16);
}

// ---------------- weight prep: wmerge UNION wconv ----------------
// blocks [0,128): Wc row r = Wve@W1 (bf16), bc = Wve@b1+bve
// blocks [128,192): Wev -> bf16

__global__ void k_wprep(const float* __restrict__ W1, const float* __restrict__ Wve,
                        const float* __restrict__ b1, const float* __restrict__ bve,
                        const float* __restrict__ Wev,
                        ushort_t* __restrict__ Wc, float* __restrict__ bc,
                        ushort_t* __restrict__ Wevb){
  int t = threadIdx.x;
  if (blockIdx.x < 128){
    int r = blockIdx.x;
    if (t < D){
      float acc = 0.f;
      for (int k = 0; k < D; ++k)
        acc += Wve[r * D + k] * W1[k * D + t];
      Wc[r * D + t] = f2bf(acc);
      if (t == 0){
        float s = 0.f;
        for (int k = 0; k < D; ++k) s += Wve[r * D + k] * b1[k];
        bc[r] = s + bve[r];
      }
    }
  } else {
    int i = (blockIdx.x - 128) * 256 + t;
    if (i < D * D) Wevb[i] = f2bf(Wev[i]);
  }
}

// ---------------- MFMA GEMM body ----------------
// out(bf16)[M x 128] = A[M x 128] @ Wb(bf16).T + bias. A is f32 or bf16.
// Tile: 64 rows x 128 cols, 4 waves; B fragments in registers; A-tile in LDS,
// XOR-swizzled (ushort col8 ^ ((row&7)<<3)).

template<bool BF16IN>
__device__ __forceinline__ void gemm_body(const void* __restrict__ A_,
                                          const ushort_t* __restrict__ Wb,
                                          const float* __restrict__ bias,
                                          ushort_t* __restrict__ out, int M,
                                          int bid, int nblocks, ushort_t* Al){
  const int t = threadIdx.x;
  const int w = t >> 6;
  const int l = t & 63;
  const int l15 = l & 15;
  const int lh = l >> 4;            // 0..3

  short8 breg[4][8];
#pragma unroll
  for (int kc = 0; kc < 4; ++kc)
#pragma unroll
    for (int n0 = 0; n0 < 8; ++n0)
      breg[kc][n0] = *(const short8*)&Wb[(n0 * 16 + l15) * D + kc * 32 + lh * 8];

  float bias_r[8];
#pragma unroll
  for (int n0 = 0; n0 < 8; ++n0) bias_r[n0] = bias[n0 * 16 + l15];

  const int r_st = t >> 2;          // staging row 0..63
  const int q_st = t & 3;           // k-quarter (32 cols)
  const int ntile = (M + 63) >> 6;

  for (int tile = bid; tile < ntile; tile += nblocks){
    const int row0 = tile << 6;
    __syncthreads();
    {
      int r = row0 + r_st;
      ushort8v h[4];
      if (r < M){
        if (BF16IN){
          const ushort8v* src = (const ushort8v*)((const ushort_t*)A_ + (size_t)r * D + q_st * 32);
#pragma unroll
          for (int c = 0; c < 4; ++c) h[c] = src[c];
        } else {
          const float4* src = (const float4*)((const float*)A_ + (size_t)r * D + q_st * 32);
          float4 v[8];
#pragma unroll
          for (int i = 0; i < 8; ++i) v[i] = src[i];
#pragma unroll
          for (int c = 0; c < 4; ++c){
            h[c][0] = f2bf(v[2*c].x);   h[c][1] = f2bf(v[2*c].y);
            h[c][2] = f2bf(v[2*c].z);   h[c][3] = f2bf(v[2*c].w);
            h[c][4] = f2bf(v[2*c+1].x); h[c][5] = f2bf(v[2*c+1].y);
            h[c][6] = f2bf(v[2*c+1].z); h[c][7] = f2bf(v[2*c+1].w);
          }
        }
      } else {
#pragma unroll
        for (int c = 0; c < 4; ++c) h[c] = (ushort8v){0,0,0,0,0,0,0,0};
      }
#pragma unroll
      for (int c = 0; c < 4; ++c){
        int col = q_st * 32 + c * 8;
        int swz = col ^ ((r_st & 7) << 3);
        *(ushort8v*)&Al[r_st * D + swz] = h[c];
      }
    }
    __syncthreads();

    f32x4 acc[8];
#pragma unroll
    for (int n0 = 0; n0 < 8; ++n0) acc[n0] = (f32x4){0.f, 0.f, 0.f, 0.f};

#pragma unroll
    for (int kc = 0; kc < 4; ++kc){
      const int arow = w * 16 + l15;
      const int acol = (kc * 32 + lh * 8) ^ ((l15 & 7) << 3);
      short8 a = *(const short8*)&Al[arow * D + acol];
#pragma unroll
      for (int n0 = 0; n0 < 8; ++n0)
        acc[n0] = __builtin_amdgcn_mfma_f32_16x16x32_bf16(a, breg[kc][n0], acc[n0], 0, 0, 0);
    }

    // C/D layout: col = lane&15, row = (lane>>4)*4 + reg
    const int rbase = row0 + w * 16 + lh * 4;
#pragma unroll
    for (int n0 = 0; n0 < 8; ++n0){
      const int colo = n0 * 16 + l15;
#pragma unroll
      for (int rg = 0; rg < 4; ++rg){
        int row = rbase + rg;
        if (row < M) out[(size_t)row * D + colo] = f2bf(acc[n0][rg] + bias_r[n0]);
      }
    }
  }
}

template<bool BF16IN>
__global__ __launch_bounds__(256, 2)
void k_gemm(const void* __restrict__ A_, const ushort_t* __restrict__ Wb,
            const float* __restrict__ bias, ushort_t* __restrict__ out, int M){
  __shared__ ushort_t Al[64 * D];
  gemm_body<BF16IN>(A_, Wb, bias, out, M, blockIdx.x, gridDim.x, Al);
}

// ---------------- U1: gemm1 (f32 in) UNION count-with-ranks ----------------
// blocks [0, GEMM_BLOCKS): gemm1 (MFMA/BW-bound)
// blocks [GEMM_BLOCKS, ...): count (atomic-latency-bound) -- complementary.

__global__ __launch_bounds__(256, 2)
void k_u1(const float* __restrict__ A, const ushort_t* __restrict__ Wb,
          const float* __restrict__ bias, ushort_t* __restrict__ out, int M,
          const int* __restrict__ node_idx, const int* __restrict__ hedge_idx, int ni,
          int* __restrict__ cnt_v, int* __restrict__ cnt_e,
          int* __restrict__ rank_v, int* __restrict__ rank_e){
  __shared__ ushort_t Al[64 * D];
  if (blockIdx.x < GEMM_BLOCKS){
    gemm_body<false>(A, Wb, bias, out, M, blockIdx.x, GEMM_BLOCKS, Al);
  } else {
    int i = (blockIdx.x - GEMM_BLOCKS) * 256 + threadIdx.x;
    if (i < ni){
      rank_v[i] = atomicAdd(&cnt_v[node_idx[i]], 1);
      rank_e[i] = atomicAdd(&cnt_e[hedge_idx[i]], 1);
    }
  }
}

// ---------------- fused scans (e then v) ----------------

__device__ __forceinline__ void scan_partial_body(const int* cnt, int n, int* bsum, int b){
  __shared__ int s[256];
  int t = threadIdx.x;
  int base = b * 1024;
  int acc = 0;
  for (int j = t; j < 1024; j += 256){
    int idx = base + j;
    if (idx < n) acc += cnt[idx];
  }
  s[t] = acc; __syncthreads();
  for (int o = 128; o > 0; o >>= 1){
    if (t < o) s[t] += s[t + o];
    __syncthreads();
  }
  if (t == 0) bsum[b] = s[0];
}

__global__ void k_scan_partial2(const int* __restrict__ cnt_e, int ne, int* __restrict__ bsum_e,
                                const int* __restrict__ cnt_v, int nv, int* __restrict__ bsum_v,
                                int nbe){
  if ((int)blockIdx.x < nbe) scan_partial_body(cnt_e, ne, bsum_e, blockIdx.x);
  else                       scan_partial_body(cnt_v, nv, bsum_v, blockIdx.x - nbe);
}

__device__ __forceinline__ void scan_bsums_body(int* bsum, int nb){
  __shared__ int s[256];
  int t = threadIdx.x;
  int runbase = 0;
  for (int base = 0; base < nb; base += 256){
    int v = (base + t < nb) ? bsum[base + t] : 0;
    s[t] = v;
    __syncthreads();
    for (int o = 1; o < 256; o <<= 1){
      int x = (t >= o) ? s[t - o] : 0;
      __syncthreads();
      s[t] += x;
      __syncthreads();
    }
    int total = s[255];
    if (base + t < nb) bsum[base + t] = runbase + (s[t] - v);  // exclusive
    __syncthreads();
    runbase += total;
  }
}

__global__ void k_scan_bsums2(int* __restrict__ bsum_e, int nbe,
                              int* __restrict__ bsum_v, int nbv){
  if (blockIdx.x == 0) scan_bsums_body(bsum_e, nbe);
  else                 scan_bsums_body(bsum_v, nbv);
}

__device__ __forceinline__ void scan_final_body(const int* cnt, int n, const int* bsum,
                                                int* off, int b){
  __shared__ int s[256];
  int t = threadIdx.x;
  int base = b * 1024 + t * 4;
  int v0 = (base + 0 < n) ? cnt[base + 0] : 0;
  int v1 = (base + 1 < n) ? cnt[base + 1] : 0;
  int v2 = (base + 2 < n) ? cnt[base + 2] : 0;
  int v3 = (base + 3 < n) ? cnt[base + 3] : 0;
  int lsum = v0 + v1 + v2 + v3;
  s[t] = lsum; __syncthreads();
  for (int o = 1; o < 256; o <<= 1){
    int x = (t >= o) ? s[t - o] : 0;
    __syncthreads();
    s[t] += x;
    __syncthreads();
  }
  int excl = s[t] - lsum + bsum[b];
  if (base + 0 < n) off[base + 0] = excl;
  if (base + 1 < n) off[base + 1] = excl + v0;
  if (base + 2 < n) off[base + 2] = excl + v0 + v1;
  if (base + 3 < n) off[base + 3] = excl + v0 + v1 + v2;
}

__global__ void k_scan_final2(const int* __restrict__ cnt_e, int ne, const int* __restrict__ bsum_e,
                              int* __restrict__ off_e,
                              const int* __restrict__ cnt_v, int nv, const int* __restrict__ bsum_v,
                              int* __restrict__ off_v, int nbe){
  if ((int)blockIdx.x < nbe) scan_final_body(cnt_e, ne, bsum_e, off_e, blockIdx.x);
  else                       scan_final_body(cnt_v, nv, bsum_v, off_v, blockIdx.x - nbe);
}

// ---------------- fill (split by consumer) ----------------

__global__ void k_fill_e(const int* __restrict__ node_idx, const int* __restrict__ hedge_idx,
                         const int* __restrict__ rank_e, int ni,
                         const int* __restrict__ off_e, int* __restrict__ elist_v){
  int i = blockIdx.x * 256 + threadIdx.x;
  if (i < ni){
    int pe = off_e[hedge_idx[i]] + rank_e[i];
    __builtin_nontemporal_store(node_idx[i], &elist_v[pe]);
  }
}

// ---------------- weighted segment gather-sum, 4 items/iter ----------------
// Wave per segment; lane-group g (16 lanes) handles item j+g; each lane loads
// 16B (8 bf16 cols); cross-group fold via shfl_xor(16/32).

template<bool BF16OUT>
__device__ __forceinline__ void scatter_body(const ushort_t* __restrict__ src,
                                             const int* __restrict__ off,
                                             const int* __restrict__ cnt,
                                             const int* __restrict__ list,
                                             const float* __restrict__ wnum,
                                             const float* __restrict__ dsum,
                                             void* __restrict__ dst_, int nseg, int gw0){
  int gw = gw0 + ((int)threadIdx.x >> 6);
  if (gw >= nseg) return;
  int lane = threadIdx.x & 63;
  int l15 = lane & 15;
  int g = lane >> 4;
  int s = __builtin_amdgcn_readfirstlane(off[gw]);
  int n = __builtin_amdgcn_readfirstlane(cnt[gw]);
  float inv = 1.0f / dsum[gw];

  float acc[8];
#pragma unroll
  for (int c = 0; c < 8; ++c) acc[c] = 0.f;

  for (int j = 0; j < n; j += 4){
    int jj = j + g;
    bool ok = jj < n;
    int r = list[s + (ok ? jj : 0)];
    float wt = ok ? wnum[r] * inv : 0.f;
    ushort8v x = *(const ushort8v*)&src[(size_t)r * D + l15 * 8];
#pragma unroll
    for (int c = 0; c < 8; ++c) acc[c] += wt * bf2f(x[c]);
  }

#pragma unroll
  for (int c = 0; c < 8; ++c){
    acc[c] += __shfl_xor(acc[c], 16);
    acc[c] += __shfl_xor(acc[c], 32);
  }

  if (g == 0){
    if (BF16OUT){
      ushort8v h;
#pragma unroll
      for (int c = 0; c < 8; ++c) h[c] = f2bf(acc[c]);
      *(ushort8v*)((ushort_t*)dst_ + (size_t)gw * D + l15 * 8) = h;
    } else {
      float* dp = (float*)dst_ + (size_t)gw * D + l15 * 8;
      float4 o0, o1;
      o0.x = acc[0]; o0.y = acc[1]; o0.z = acc[2]; o0.w = acc[3];
      o1.x = acc[4]; o1.y = acc[5]; o1.z = acc[6]; o1.w = acc[7];
      *(float4*)dp = o0;
      *(float4*)(dp + 4) = o1;
    }
  }
}

template<bool BF16OUT>
__global__ void k_scatter4(const ushort_t* __restrict__ src,
                           const int* __restrict__ off, const int* __restrict__ cnt,
                           const int* __restrict__ list,
                           const float* __restrict__ wnum, const float* __restrict__ dsum,
                           void* __restrict__ dst_, int nseg){
  scatter_body<BF16OUT>(src, off, cnt, list, wnum, dsum, dst_, nseg, blockIdx.x * 4);
}

// ---------------- U2: scatter1 (read-bound) UNION fill_v (write-bound) ----------

__global__ void k_u2(const ushort_t* __restrict__ src,
                     const int* __restrict__ off, const int* __restrict__ cnt,
                     const int* __restrict__ list,
                     const float* __restrict__ wnum, const float* __restrict__ dsum,
                     void* __restrict__ dst_, int nseg, int nsb,
                     const int* __restrict__ node_idx, const int* __restrict__ hedge_idx,
                     const int* __restrict__ rank_v, int ni,
                     const int* __restrict__ off_v, int* __restrict__ vlist_e){
  if ((int)blockIdx.x < nsb){
    scatter_body<true>(src, off, cnt, list, wnum, dsum, dst_, nseg, blockIdx.x * 4);
  } else {
    int i = (blockIdx.x - nsb) * 256 + threadIdx.x;
    if (i < ni){
      int pv = off_v[node_idx[i]] + rank_v[i];
      __builtin_nontemporal_store(hedge_idx[i], &vlist_e[pv]);
    }
  }
}

// ---------------- host ----------------

static inline int cdiv(int a, int b){ return (a + b - 1) / b; }

extern "C" void kernel_launch(void* const* d_in, const int* in_sizes, int n_in,
                              void* d_out, int out_size, void* d_ws, size_t ws_size,
                              hipStream_t stream){
  const float* vfeat        = (const float*)d_in[0];
  const float* v_reg_weight = (const float*)d_in[2];
  const float* v_reg_sum    = (const float*)d_in[3];
  const float* e_reg_weight = (const float*)d_in[4];
  const float* e_reg_sum    = (const float*)d_in[5];
  const int*   node_idx     = (const int*)d_in[6];
  const int*   hedge_idx    = (const int*)d_in[7];
  const float* W1  = (const float*)d_in[8];
  const float* b1  = (const float*)d_in[9];
  const float* Wve = (const float*)d_in[10];
  const float* bve = (const float*)d_in[11];
  const float* Wev = (const float*)d_in[12];
  const float* bev = (const float*)d_in[13];

  const int NV = in_sizes[2];
  const int NE = in_sizes[4];
  const int NI = in_sizes[6];

  char* p = (char*)d_ws;
  auto alloc = [&](size_t nbytes) -> void* {
    void* q = (void*)p;
    p += (nbytes + 255) & ~(size_t)255;
    return q;
  };

  char* zstart = p;
  int* cnt_v = (int*)alloc((size_t)NV * 4);
  int* cnt_e = (int*)alloc((size_t)NE * 4);
  size_t zbytes = (size_t)(p - zstart);

  int* off_v  = (int*)alloc((size_t)NV * 4);
  int* off_e  = (int*)alloc((size_t)NE * 4);
  int* bsum_e = (int*)alloc(1024 * 4);
  int* bsum_v = (int*)alloc(1024 * 4);
  int* rank_v = (int*)alloc((size_t)NI * 4);
  int* rank_e = (int*)alloc((size_t)NI * 4);
  int* vlist_e = (int*)alloc((size_t)NI * 4);   // per vertex-slot: edge id
  int* elist_v = (int*)alloc((size_t)NI * 4);   // per edge-slot: vertex id
  ushort_t* Wc   = (ushort_t*)alloc((size_t)D * D * 2);
  ushort_t* Wevb = (ushort_t*)alloc((size_t)D * D * 2);
  float* bc      = (float*)alloc((size_t)D * 4);
  ushort_t* feat_e = (ushort_t*)alloc((size_t)NE * D * 2);
  ushort_t* Wh_e   = (ushort_t*)alloc((size_t)NE * D * 2);

  // Wh_n (bf16) lives in d_out's storage; fully overwritten by final scatter.
  ushort_t* Wh_n = (ushort_t*)d_out;

  hipMemsetAsync(zstart, 0, zbytes, stream);

  // weight prep (tiny): Wc/bc + Wev->bf16
  k_wprep<<<192, 256, 0, stream>>>(W1, Wve, b1, bve, Wev, Wc, bc, Wevb);

  // U1: gemm1 (blocks 0..511) UNION count-with-ranks (atomic-bound)
  k_u1<<<GEMM_BLOCKS + cdiv(NI, 256), 256, 0, stream>>>(vfeat, Wc, bc, Wh_n, NV,
                                                        node_idx, hedge_idx, NI,
                                                        cnt_v, cnt_e, rank_v, rank_e);

  int nbe = cdiv(NE, 1024), nbv = cdiv(NV, 1024);
  k_scan_partial2<<<nbe + nbv, 256, 0, stream>>>(cnt_e, NE, bsum_e, cnt_v, NV, bsum_v, nbe);
  k_scan_bsums2<<<2, 256, 0, stream>>>(bsum_e, nbe, bsum_v, nbv);
  k_scan_final2<<<nbe + nbv, 256, 0, stream>>>(cnt_e, NE, bsum_e, off_e,
                                               cnt_v, NV, bsum_v, off_v, nbe);

  // fill_e: elist_v (needed by scatter1)
  k_fill_e<<<cdiv(NI, 256), 256, 0, stream>>>(node_idx, hedge_idx, rank_e, NI,
                                              off_e, elist_v);

  // U2: scatter1 (node->hyperedge, read-bound) UNION fill_v (write-bound)
  int nsb = cdiv(NE, 4);   // scatter blocks: 4 segments (waves) per block
  k_u2<<<nsb + cdiv(NI, 256), 256, 0, stream>>>(Wh_n, off_e, cnt_e, elist_v,
                                                v_reg_weight, e_reg_sum, feat_e, NE, nsb,
                                                node_idx, hedge_idx, rank_v, NI,
                                                off_v, vlist_e);

  // edge linear: Wh_e (bf16) = feat_e @ Wev.T + bev
  int g2 = cdiv(NE, 64); if (g2 > 512) g2 = 512;
  k_gemm<true><<<g2, 256, 0, stream>>>(feat_e, Wevb, bev, Wh_e, NE);

  // hyperedge -> node: d_out (f32)
  k_scatter4<false><<<cdiv(NV, 4), 256, 0, stream>>>(Wh_e, off_v, cnt_v, vlist_e,
                                                     e_reg_weight, v_reg_sum,
                                                     d_out, NV);
}